// Round 1
// 571.475 us; speedup vs baseline: 1.2078x; 1.2078x over previous
//
#include <hip/hip_runtime.h>
#include <hip/hip_bf16.h>
#include <math.h>

#define O_ 1024
#define D_ 1024
#define E_ 16
#define K_ 4
#define H_ 2048
#define A_ 64
#define LOSS_COEF 0.01f

// np reference runs FTZ/DAZ (its min logprob is log(FLT_MIN)); gfx950 keeps
// IEEE denormals. Software-flush at the two decision points. (R1-verified.)
#define FLT_MIN_NORMAL 1.17549435e-38f

using floatx4 = __attribute__((ext_vector_type(4))) float;
using fragb   = __attribute__((ext_vector_type(8))) short;   // 8 bf16 in 4 VGPRs

static __device__ __forceinline__ ushort f2bf(float f) {
    // round-to-nearest-even fp32 -> bf16
    unsigned u = __builtin_bit_cast(unsigned, f);
    u += 0x7fffu + ((u >> 16) & 1u);
    return (ushort)(u >> 16);
}

// async global->LDS, 16B per lane; LDS dest = wave-uniform base + lane*16,
// global src is per-lane (so gathers + pre-swizzled sources are fine).
static __device__ __forceinline__ void gld_lds16(const void* g, void* l) {
    __builtin_amdgcn_global_load_lds(
        (const __attribute__((address_space(1))) void*)g,
        (__attribute__((address_space(3))) void*)l, 16, 0, 0);
}

// ---------------------------------------------------------------------------
// gating (fp32: top-k selection + FTZ path are bf16-intolerant)
// ---------------------------------------------------------------------------
__global__ __launch_bounds__(256) void gating_kernel(
    const float* __restrict__ obs, const float* __restrict__ w_gate,
    int* __restrict__ topk_idx, float* __restrict__ topk_gate,
    float* __restrict__ imp, float* __restrict__ loadv)
{
    const int o = blockIdx.x;
    const int t = threadIdx.x;
    __shared__ float xs[D_];
    __shared__ float part[64][20];     // [d-group][e] padded (f4 bank spread)
    __shared__ float logits[E_];

    const float4* xrow = (const float4*)(obs + (size_t)o * D_);
    for (int i = t; i < D_ / 4; i += 256) ((float4*)xs)[i] = xrow[i];
    __syncthreads();

    const int dg = t >> 2, e4 = t & 3;
    const float4* wg = (const float4*)(w_gate + (size_t)o * (D_ * E_));
    float4 acc = make_float4(0.f, 0.f, 0.f, 0.f);
    #pragma unroll 4
    for (int i = 0; i < 16; ++i) {
        int d = dg + (i << 6);
        float4 w = wg[d * 4 + e4];     // f4 idx = t + 256*i : coalesced 16B/lane
        float x = xs[d];
        acc.x += x * w.x; acc.y += x * w.y; acc.z += x * w.z; acc.w += x * w.w;
    }
    *(float4*)&part[dg][e4 * 4] = acc;
    __syncthreads();
    if (t < E_) {
        float s = 0.f;
        for (int g = 0; g < 64; ++g) s += part[g][t];
        logits[t] = s;
    }
    __syncthreads();
    if (t == 0) {
        float lv[E_];
        #pragma unroll
        for (int i = 0; i < E_; ++i) lv[i] = logits[i];
        int idx[K_]; float val[K_];
        bool used[E_] = {};
        for (int k = 0; k < K_; ++k) {            // desc, ties -> lower idx
            int bi = 0; float bv = -INFINITY;
            for (int i = 0; i < E_; ++i)
                if (!used[i] && lv[i] > bv) { bv = lv[i]; bi = i; }
            used[bi] = true; idx[k] = bi; val[k] = bv;
        }
        float m = val[0];
        float ex[K_]; float s = 0.f;
        for (int k = 0; k < K_; ++k) { ex[k] = expf(val[k] - m); s += ex[k]; }
        float inv = 1.f / s;
        float sumg = 0.f; int ld = 0;
        for (int k = 0; k < K_; ++k) {
            float g = ex[k] * inv;
            topk_idx[o * K_ + k] = idx[k];
            topk_gate[o * K_ + k] = g;
            sumg += g;
            if (g > 0.f) ld++;
        }
        imp[o] = sumg;
        loadv[o] = (float)ld;
    }
}

// ---------------------------------------------------------------------------
__global__ void zero_cnt_kernel(int* __restrict__ cnt)
{
    if (threadIdx.x < E_) cnt[threadIdx.x] = 0;
}

__global__ __launch_bounds__(256) void build_dispatch_kernel(
    const int* __restrict__ topk_idx, const float* __restrict__ topk_gate,
    int* __restrict__ cnt, int* __restrict__ rows, float* __restrict__ gatev)
{
    int i = blockIdx.x * 256 + threadIdx.x;      // 0..O*K-1
    int e = topk_idx[i];
    int pos = atomicAdd(&cnt[e], 1);
    rows[e * O_ + pos] = i >> 2;
    gatev[e * O_ + pos] = topk_gate[i];
}

// y[o,a] = sum_k gate[o,k]*b2[e_k,a]  (init; MFMA kernel atomicAdds on top)
__global__ __launch_bounds__(64) void y_init_kernel(
    const int* __restrict__ topk_idx, const float* __restrict__ topk_gate,
    const float* __restrict__ b2, float* __restrict__ y)
{
    int o = blockIdx.x, a = threadIdx.x;
    float acc = 0.f;
    #pragma unroll
    for (int k = 0; k < K_; ++k) {
        int e = topk_idx[o * K_ + k];
        acc += topk_gate[o * K_ + k] * b2[e * A_ + a];
    }
    y[(size_t)o * A_ + a] = acc;
}

// ---------------------------------------------------------------------------
__global__ __launch_bounds__(1024) void loss_kernel(
    const float* __restrict__ imp, const float* __restrict__ loadv,
    float* __restrict__ out_loss)
{
    __shared__ float s1[1024], s2[1024];
    __shared__ float mean1, mean2;
    int t = threadIdx.x;
    float a = imp[t], b = loadv[t];
    s1[t] = a; s2[t] = b; __syncthreads();
    for (int s = 512; s > 0; s >>= 1) {
        if (t < s) { s1[t] += s1[t + s]; s2[t] += s2[t + s]; }
        __syncthreads();
    }
    if (t == 0) { mean1 = s1[0] / O_; mean2 = s2[0] / O_; }
    __syncthreads();
    float d1 = a - mean1, d2 = b - mean2;
    s1[t] = d1 * d1; s2[t] = d2 * d2; __syncthreads();
    for (int s = 512; s > 0; s >>= 1) {
        if (t < s) { s1[t] += s1[t + s]; s2[t] += s2[t + s]; }
        __syncthreads();
    }
    if (t == 0) {
        float var1 = s1[0] / (O_ - 1), var2 = s2[0] / (O_ - 1);
        const float eps = 1e-10f;
        out_loss[0] = (var1 / (mean1 * mean1 + eps) + var2 / (mean2 * mean2 + eps)) * LOSS_COEF;
    }
}

// ---------------------------------------------------------------------------
// conversions: obs -> bf16; src[E][R][C] f32 -> dst[E][C][R] bf16 (transpose)
// ---------------------------------------------------------------------------
__global__ __launch_bounds__(256) void cvt_obs_kernel(
    const float* __restrict__ src, ushort* __restrict__ dst)
{
    int i = blockIdx.x * 256 + threadIdx.x;       // float4 index
    float4 v = ((const float4*)src)[i];
    ushort4 u;
    u.x = f2bf(v.x); u.y = f2bf(v.y); u.z = f2bf(v.z); u.w = f2bf(v.w);
    ((ushort4*)dst)[i] = u;
}

__global__ __launch_bounds__(256) void transpose_bf16_kernel(
    const float* __restrict__ src, ushort* __restrict__ dst, int R, int C)
{
    const int c0 = blockIdx.x * 64, r0 = blockIdx.y * 64, e = blockIdx.z;
    __shared__ ushort tile[64][72];               // +8 pad
    const float* s = src + (size_t)e * R * C;
    const int t = threadIdx.x;
    const int rr = t >> 4, cq = t & 15;
    #pragma unroll
    for (int i = 0; i < 4; ++i) {
        int r = rr + i * 16;
        float4 v = *(const float4*)(s + (size_t)(r0 + r) * C + c0 + cq * 4);
        ushort4 u;
        u.x = f2bf(v.x); u.y = f2bf(v.y); u.z = f2bf(v.z); u.w = f2bf(v.w);
        *(ushort4*)&tile[r][cq * 4] = u;
    }
    __syncthreads();
    ushort* dbase = dst + (size_t)e * R * C;
    const int cc = t >> 4, rq = t & 15;
    #pragma unroll
    for (int i = 0; i < 4; ++i) {
        int c = cc + i * 16;
        ushort4 u;
        u.x = tile[rq * 4 + 0][c];
        u.y = tile[rq * 4 + 1][c];
        u.z = tile[rq * 4 + 2][c];
        u.w = tile[rq * 4 + 3][c];
        *(ushort4*)(dbase + (size_t)(c0 + c) * R + r0 + rq * 4) = u;
    }
}

// ---------------------------------------------------------------------------
// fused expert MLP, bf16 MFMA 16x16x32 — LDS-staged, double-buffered.
//   tile: 128 dispatched rows x 128 h, BK=64, 4 waves (2x2) of 64x64 each.
//   layer1: h = relu(X_e @ w1[e] + b1[e]) * gate  (A,B staged via
//           global_load_lds width=16, 2-phase pipeline: STAGE(t+1) ||
//           COMPUTE(t) -> __syncthreads() per chunk)
//   layer2: y += h @ w2[e]  (Hs overlays the staging buffers; K=128 local)
// LDS layout (T2/rule#21): LDS[r][cb] holds global[r][cb ^ (r&7)] (cb =
// 16B-block in a 128B row). gload_lds writes linearly, so the XOR is applied
// to the per-lane GLOBAL source; reads XOR the block index with row&7.
// 65.5 KB LDS -> 2 blocks/CU; staging for chunk t+1 flies under MFMA of t.
// ---------------------------------------------------------------------------
__global__ __launch_bounds__(256, 2) void expert_mfma_kernel(
    const ushort* __restrict__ obs_bf, const ushort* __restrict__ w1T,
    const float* __restrict__ b1, const ushort* __restrict__ w2T,
    const int* __restrict__ cnt, const int* __restrict__ rows,
    const float* __restrict__ gatev, float* __restrict__ y)
{
    const int ht = blockIdx.x, rt = blockIdx.y, e = blockIdx.z;
    const int n = cnt[e];
    if (rt * 128 >= n) return;                    // uniform early-exit

    const int t = threadIdx.x, wv = t >> 6, l = t & 63;
    const int lm = l & 15, q = l >> 4;
    const int wr = wv >> 1, wc = wv & 1;          // 2x2 wave grid

    __shared__ __align__(16) ushort smem[32768];  // A dbuf 32KB | B dbuf 32KB; reused as Hs[128][136]
    __shared__ int   rid_s[128];
    __shared__ float rgate_s[128];
    __shared__ float b1s[128];

    if (t < 128) {
        int gi = rt * 128 + t;
        rid_s[t]   = (gi < n) ? rows[e * O_ + gi]  : -1;
        rgate_s[t] = (gi < n) ? gatev[e * O_ + gi] : 0.f;   // gate=0 kills junk rows
    } else {
        b1s[t - 128] = b1[e * H_ + ht * 128 + (t - 128)];
    }
    __syncthreads();

    // staging geometry: wave-load j (0..3) covers LDS 16B-slots s=(j*4+wv)*64+l;
    // r = s>>3 = (j*4+wv)*8 + (l>>3), cb = l&7; src col-block = cb ^ (r&7).
    const int swe = ((l & 7) ^ (l >> 3)) << 3;    // src column swizzle (ushorts)
    const ushort* asrc[4];
    const ushort* bsrc[4];
    #pragma unroll
    for (int j = 0; j < 4; ++j) {
        int r = (j * 4 + wv) * 8 + (l >> 3);
        int arow = rid_s[r]; if (arow < 0) arow = 0;
        asrc[j] = obs_bf + (size_t)arow * D_ + swe;
        bsrc[j] = w1T + ((size_t)(e * H_ + ht * 128 + r)) * D_ + swe;
    }

    auto stage = [&](int b, int kc) {
        ushort* ab_ = &smem[b * 8192];
        ushort* bb_ = &smem[16384 + b * 8192];
        const int ko = kc * 64;                   // ushorts
        #pragma unroll
        for (int j = 0; j < 4; ++j) {
            gld_lds16(asrc[j] + ko, ab_ + (j * 4 + wv) * 512);
            gld_lds16(bsrc[j] + ko, bb_ + (j * 4 + wv) * 512);
        }
    };

    // ---- layer 1 main loop: acc[rt][nt] over K=1024 in 16 BK=64 chunks
    floatx4 acc[4][4] = {};
    int buf = 0;
    stage(0, 0);
    __syncthreads();                              // drains vmcnt -> chunk 0 ready

    for (int kc = 0; kc < 16; ++kc) {
        if (kc < 15) stage(buf ^ 1, kc + 1);      // prefetch under compute
        const ushort* ab = &smem[buf * 8192];
        const ushort* bb = &smem[16384 + buf * 8192];
        #pragma unroll
        for (int ks = 0; ks < 2; ++ks) {
            const int co = ((ks * 4 + q) ^ (lm & 7)) << 3;   // row&7 == lm&7
            fragb a[4];
            #pragma unroll
            for (int i = 0; i < 4; ++i)
                a[i] = *(const fragb*)(ab + (wr * 64 + i * 16 + lm) * 64 + co);
            #pragma unroll
            for (int nt = 0; nt < 4; ++nt) {
                fragb b = *(const fragb*)(bb + (wc * 64 + nt * 16 + lm) * 64 + co);
                #pragma unroll
                for (int i = 0; i < 4; ++i)
                    acc[i][nt] = __builtin_amdgcn_mfma_f32_16x16x32_bf16(a[i], b, acc[i][nt], 0, 0, 0);
            }
        }
        __syncthreads();                          // joins waves + drains next-chunk stage
        buf ^= 1;
    }

    // ---- epilogue 1: relu(acc+b1)*gate -> Hs[128][136] bf16 (overlays smem)
    ushort* Hs = smem;
    #pragma unroll
    for (int i = 0; i < 4; ++i) {
        #pragma unroll
        for (int nt = 0; nt < 4; ++nt) {
            const int col = wc * 64 + nt * 16 + lm;
            const float bb = b1s[col];
            #pragma unroll
            for (int r = 0; r < 4; ++r) {
                const int row = wr * 64 + i * 16 + q * 4 + r;   // C: col=lm, row=q*4+reg
                float h = acc[i][nt][r] + bb;
                h = h > 0.f ? h : 0.f;
                Hs[row * 136 + col] = f2bf(h * rgate_s[row]);
            }
        }
    }
    __syncthreads();

    // ---- layer 2: y-tile 128x64; wave: rows wr*64 (4 rt) x a-cols wc*32 (2 nt); K=128
    floatx4 acc2[4][2] = {};
    #pragma unroll
    for (int ks = 0; ks < 4; ++ks) {
        fragb a[4];
        #pragma unroll
        for (int i = 0; i < 4; ++i)
            a[i] = *(const fragb*)(Hs + (wr * 64 + i * 16 + lm) * 136 + ks * 32 + q * 8);
        #pragma unroll
        for (int nt = 0; nt < 2; ++nt) {
            const int acol = wc * 32 + nt * 16 + lm;
            fragb b = *(const fragb*)(w2T + ((size_t)(e * A_ + acol)) * H_ + ht * 128 + ks * 32 + q * 8);
            #pragma unroll
            for (int i = 0; i < 4; ++i)
                acc2[i][nt] = __builtin_amdgcn_mfma_f32_16x16x32_bf16(a[i], b, acc2[i][nt], 0, 0, 0);
        }
    }

    // ---- epilogue 2: scatter-add into y
    #pragma unroll
    for (int i = 0; i < 4; ++i) {
        #pragma unroll
        for (int r = 0; r < 4; ++r) {
            const int row = wr * 64 + i * 16 + q * 4 + r;
            const int orow = rid_s[row];
            if (orow >= 0) {
                #pragma unroll
                for (int nt = 0; nt < 2; ++nt)
                    atomicAdd(&y[(size_t)orow * A_ + wc * 32 + nt * 16 + lm], acc2[i][nt][r]);
            }
        }
    }
}

// ---------------------------------------------------------------------------
// action head (fp32; software-FTZ decides the p==0 -> log(1e-8) branch)
// ---------------------------------------------------------------------------
__global__ __launch_bounds__(256) void action_head_kernel(
    const float* __restrict__ obs, const float* __restrict__ last_w,
    const float* __restrict__ last_b,
    float* __restrict__ probs, float* __restrict__ logprobs)
{
    const int o = blockIdx.x;
    const int t = threadIdx.x;
    __shared__ float xs[D_];
    __shared__ float red[16][A_];

    const float4* xrow = (const float4*)(obs + (size_t)o * D_);
    for (int i = t; i < D_ / 4; i += 256) ((float4*)xs)[i] = xrow[i];
    __syncthreads();

    const int a4 = t & 15, dg = t >> 4;
    const float* lw = last_w + (size_t)o * (D_ * A_);
    float acc0 = 0.f, acc1 = 0.f, acc2 = 0.f, acc3 = 0.f;
    #pragma unroll 8
    for (int i = 0; i < D_ / 16; ++i) {
        int d = dg + (i << 4);
        float4 w = *(const float4*)(lw + (size_t)d * A_ + a4 * 4);  // coalesced
        float x = xs[d];
        acc0 += x * w.x; acc1 += x * w.y; acc2 += x * w.z; acc3 += x * w.w;
    }
    *(float4*)&red[dg][a4 * 4] = make_float4(acc0, acc1, acc2, acc3);
    __syncthreads();

    if (t < A_) {   // one wave does the softmax
        float mu = last_b[(size_t)o * A_ + t];
        #pragma unroll
        for (int g = 0; g < 16; ++g) mu += red[g][t];
        float mx = mu;
        #pragma unroll
        for (int off = 32; off > 0; off >>= 1) mx = fmaxf(mx, __shfl_xor(mx, off, 64));
        float ex = expf(mu - mx);
        if (ex < FLT_MIN_NORMAL) ex = 0.f;            // software FTZ
        float s = ex;
        #pragma unroll
        for (int off = 32; off > 0; off >>= 1) s += __shfl_xor(s, off, 64);
        float p = ex / s;
        if (p < FLT_MIN_NORMAL) p = 0.f;              // software FTZ
        probs[(size_t)o * A_ + t] = p;
        float z = (p == 0.f) ? 1e-8f : 0.f;
        logprobs[(size_t)o * A_ + t] = logf(p + z);
    }
}

// ---------------------------------------------------------------------------
extern "C" void kernel_launch(void* const* d_in, const int* in_sizes, int n_in,
                              void* d_out, int out_size, void* d_ws, size_t ws_size,
                              hipStream_t stream)
{
    const float* obs    = (const float*)d_in[0];
    const float* w_gate = (const float*)d_in[1];
    const float* w1     = (const float*)d_in[2];
    const float* b1     = (const float*)d_in[3];
    const float* w2     = (const float*)d_in[4];
    const float* b2     = (const float*)d_in[5];
    const float* last_w = (const float*)d_in[6];
    const float* last_b = (const float*)d_in[7];

    float* out   = (float*)d_out;
    float* probs = out;                 // [O,A]
    float* logp  = out + O_ * A_;       // [O,A]
    float* yout  = out + 2 * O_ * A_;   // [O,A]
    float* loss  = out + 3 * O_ * A_;   // [1]

    char* ws = (char*)d_ws;
    int*    topk_idx  = (int*)(ws);                         // 16 KB
    float*  topk_gate = (float*)(ws + (16 << 10));          // 16 KB
    float*  imp       = (float*)(ws + (32 << 10));          // 4 KB
    float*  loadv     = (float*)(ws + (36 << 10));          // 4 KB
    int*    cnt       = (int*)(ws + (40 << 10));            // 64 B
    int*    rows      = (int*)(ws + (41 << 10));            // 64 KB
    float*  gatev     = (float*)(ws + (105 << 10));         // 64 KB
    ushort* obs_bf    = (ushort*)(ws + (256 << 10));        // 2 MB
    ushort* w1T       = (ushort*)(ws + (256 << 10) + (2 << 20));   // 64 MB
    ushort* w2T       = (ushort*)(ws + (256 << 10) + (66 << 20));  // 4 MB

    hipLaunchKernelGGL(zero_cnt_kernel, dim3(1), dim3(64), 0, stream, cnt);
    hipLaunchKernelGGL(gating_kernel, dim3(O_), dim3(256), 0, stream,
                       obs, w_gate, topk_idx, topk_gate, imp, loadv);
    hipLaunchKernelGGL(build_dispatch_kernel, dim3((O_ * K_) / 256), dim3(256), 0, stream,
                       topk_idx, topk_gate, cnt, rows, gatev);
    hipLaunchKernelGGL(y_init_kernel, dim3(O_), dim3(A_), 0, stream,
                       topk_idx, topk_gate, b2, yout);
    hipLaunchKernelGGL(loss_kernel, dim3(1), dim3(1024), 0, stream, imp, loadv, loss);

    hipLaunchKernelGGL(cvt_obs_kernel, dim3((O_ * D_) / 1024), dim3(256), 0, stream,
                       obs, obs_bf);
    hipLaunchKernelGGL(transpose_bf16_kernel, dim3(H_ / 64, D_ / 64, E_), dim3(256), 0, stream,
                       w1, w1T, D_, H_);
    hipLaunchKernelGGL(transpose_bf16_kernel, dim3(A_ / 64, H_ / 64, E_), dim3(256), 0, stream,
                       w2, w2T, H_, A_);

    hipLaunchKernelGGL(expert_mfma_kernel, dim3(H_ / 128, O_ / 128, E_), dim3(256), 0, stream,
                       obs_bf, w1T, b1, w2T, cnt, rows, gatev, yout);
    hipLaunchKernelGGL(action_head_kernel, dim3(O_), dim3(256), 0, stream,
                       obs, last_w, last_b, probs, logp);
}

// Round 2
// 569.773 us; speedup vs baseline: 1.2115x; 1.0030x over previous
//
#include <hip/hip_runtime.h>
#include <hip/hip_bf16.h>
#include <math.h>

#define O_ 1024
#define D_ 1024
#define E_ 16
#define K_ 4
#define H_ 2048
#define A_ 64
#define LOSS_COEF 0.01f

// np reference runs FTZ/DAZ (its min logprob is log(FLT_MIN)); gfx950 keeps
// IEEE denormals. Software-flush at the two decision points. (R1-verified.)
#define FLT_MIN_NORMAL 1.17549435e-38f

using floatx4 = __attribute__((ext_vector_type(4))) float;
using fragb   = __attribute__((ext_vector_type(8))) short;   // 8 bf16 in 4 VGPRs

static __device__ __forceinline__ ushort f2bf(float f) {
    // round-to-nearest-even fp32 -> bf16
    unsigned u = __builtin_bit_cast(unsigned, f);
    u += 0x7fffu + ((u >> 16) & 1u);
    return (ushort)(u >> 16);
}

// async global->LDS, 16B per lane; LDS dest = wave-uniform base + lane*16,
// global src is per-lane (so gathers + pre-swizzled sources are fine).
static __device__ __forceinline__ void gld_lds16(const void* g, void* l) {
    __builtin_amdgcn_global_load_lds(
        (const __attribute__((address_space(1))) void*)g,
        (__attribute__((address_space(3))) void*)l, 16, 0, 0);
}

// ---------------------------------------------------------------------------
// K1 "prep": zero_cnt (block 0) + transpose w1 (8192 blocks) + transpose w2
// (512 blocks). src[E][R][C] f32 -> dst[E][C][R] bf16.
// ---------------------------------------------------------------------------
__global__ __launch_bounds__(256) void prep_kernel(
    const float* __restrict__ w1, const float* __restrict__ w2,
    ushort* __restrict__ w1T, ushort* __restrict__ w2T, int* __restrict__ cnt)
{
    const int bid = blockIdx.x;
    if (bid == 0) {
        if (threadIdx.x < E_) cnt[threadIdx.x] = 0;
        return;
    }
    int id = bid - 1;
    const float* src; ushort* dst; int R, C, c0, r0, e;
    if (id < 8192) {                      // w1: R=D, C=H
        c0 = (id & 31) * 64; r0 = ((id >> 5) & 15) * 64; e = id >> 9;
        src = w1; dst = w1T; R = D_; C = H_;
    } else {                              // w2: R=H, C=A (one c-tile)
        id -= 8192;
        c0 = 0; r0 = (id & 31) * 64; e = id >> 5;
        src = w2; dst = w2T; R = H_; C = A_;
    }

    __shared__ ushort tile[64][72];       // +8 pad
    const float* s = src + (size_t)e * R * C;
    const int t = threadIdx.x;
    const int rr = t >> 4, cq = t & 15;
    #pragma unroll
    for (int i = 0; i < 4; ++i) {
        int r = rr + i * 16;
        float4 v = *(const float4*)(s + (size_t)(r0 + r) * C + c0 + cq * 4);
        ushort4 u;
        u.x = f2bf(v.x); u.y = f2bf(v.y); u.z = f2bf(v.z); u.w = f2bf(v.w);
        *(ushort4*)&tile[r][cq * 4] = u;
    }
    __syncthreads();
    ushort* dbase = dst + (size_t)e * R * C;
    const int cc = t >> 4, rq = t & 15;
    #pragma unroll
    for (int i = 0; i < 4; ++i) {
        int c = cc + i * 16;
        ushort4 u;
        u.x = tile[rq * 4 + 0][c];
        u.y = tile[rq * 4 + 1][c];
        u.z = tile[rq * 4 + 2][c];
        u.w = tile[rq * 4 + 3][c];
        *(ushort4*)(dbase + (size_t)(c0 + c) * R + r0 + rq * 4) = u;
    }
}

// ---------------------------------------------------------------------------
// K2 "gating" (fp32: top-k + FTZ are bf16-intolerant). Fuses:
//   - build_dispatch (thread 0 scatters its 4 (row,gate) pairs directly;
//     within-expert row order is atomic-nondeterministic either way)
//   - y_init        (t<64: y[o,a] = sum_k gate_k * b2[e_k,a])
//   - cvt_obs       (row already staged in LDS -> write back bf16)
// ---------------------------------------------------------------------------
__global__ __launch_bounds__(256) void gating_kernel(
    const float* __restrict__ obs, const float* __restrict__ w_gate,
    const float* __restrict__ b2,
    int* __restrict__ cnt, int* __restrict__ rows, float* __restrict__ gatev,
    float* __restrict__ imp, float* __restrict__ loadv,
    ushort* __restrict__ obs_bf, float* __restrict__ yout)
{
    const int o = blockIdx.x;
    const int t = threadIdx.x;
    __shared__ float xs[D_];
    __shared__ float part[64][20];     // [d-group][e] padded (f4 bank spread)
    __shared__ float logits[E_];
    __shared__ int   sidx[K_];
    __shared__ float sgate[K_];

    const float4* xrow = (const float4*)(obs + (size_t)o * D_);
    for (int i = t; i < D_ / 4; i += 256) ((float4*)xs)[i] = xrow[i];
    __syncthreads();

    const int dg = t >> 2, e4 = t & 3;
    const float4* wg = (const float4*)(w_gate + (size_t)o * (D_ * E_));
    float4 acc = make_float4(0.f, 0.f, 0.f, 0.f);
    #pragma unroll 4
    for (int i = 0; i < 16; ++i) {
        int d = dg + (i << 6);
        float4 w = wg[d * 4 + e4];     // f4 idx = t + 256*i : coalesced 16B/lane
        float x = xs[d];
        acc.x += x * w.x; acc.y += x * w.y; acc.z += x * w.z; acc.w += x * w.w;
    }
    *(float4*)&part[dg][e4 * 4] = acc;
    __syncthreads();
    if (t < E_) {
        float s = 0.f;
        for (int g = 0; g < 64; ++g) s += part[g][t];
        logits[t] = s;
    }
    __syncthreads();
    if (t == 0) {
        float lv[E_];
        #pragma unroll
        for (int i = 0; i < E_; ++i) lv[i] = logits[i];
        int idx[K_]; float val[K_];
        bool used[E_] = {};
        for (int k = 0; k < K_; ++k) {            // desc, ties -> lower idx
            int bi = 0; float bv = -INFINITY;
            for (int i = 0; i < E_; ++i)
                if (!used[i] && lv[i] > bv) { bv = lv[i]; bi = i; }
            used[bi] = true; idx[k] = bi; val[k] = bv;
        }
        float m = val[0];
        float ex[K_]; float s = 0.f;
        for (int k = 0; k < K_; ++k) { ex[k] = expf(val[k] - m); s += ex[k]; }
        float inv = 1.f / s;
        float sumg = 0.f; int ld = 0;
        for (int k = 0; k < K_; ++k) {
            float g = ex[k] * inv;
            sidx[k] = idx[k]; sgate[k] = g;
            int pos = atomicAdd(&cnt[idx[k]], 1);
            rows[idx[k] * O_ + pos]  = o;
            gatev[idx[k] * O_ + pos] = g;
            sumg += g;
            if (g > 0.f) ld++;
        }
        imp[o] = sumg;
        loadv[o] = (float)ld;
    }

    // fused cvt_obs: xs -> bf16 row (overlaps thread-0 top-k)
    {
        float4 v = ((const float4*)xs)[t];        // 256 f4 = 1024 floats
        ushort4 u;
        u.x = f2bf(v.x); u.y = f2bf(v.y); u.z = f2bf(v.z); u.w = f2bf(v.w);
        ((ushort4*)(obs_bf + (size_t)o * D_))[t] = u;
    }
    __syncthreads();

    // fused y_init: y[o,a] = sum_k gate_k * b2[e_k,a]
    if (t < A_) {
        float accy = 0.f;
        #pragma unroll
        for (int k = 0; k < K_; ++k)
            accy += sgate[k] * b2[sidx[k] * A_ + t];
        yout[(size_t)o * A_ + t] = accy;
    }
}

// ---------------------------------------------------------------------------
// K3 "mega": block 0 = loss; blocks 1..2048 = expert MLP (early-exit);
// blocks 2049..3072 = action head. Expert path byte-identical to the
// R1-verified kernel (only blockIdx flattening changed). Heterogeneous
// co-residency: action's streaming reads hide expert's barrier/vmcnt stalls.
// LDS sum across paths ~77 KB -> 2 blocks/CU (as before).
// ---------------------------------------------------------------------------
__global__ __launch_bounds__(256, 2) void mega_kernel(
    const ushort* __restrict__ obs_bf, const ushort* __restrict__ w1T,
    const float* __restrict__ b1, const ushort* __restrict__ w2T,
    const int* __restrict__ cnt, const int* __restrict__ rows,
    const float* __restrict__ gatev, float* __restrict__ y,
    const float* __restrict__ obs, const float* __restrict__ last_w,
    const float* __restrict__ last_b,
    float* __restrict__ probs, float* __restrict__ logprobs,
    const float* __restrict__ imp, const float* __restrict__ loadv,
    float* __restrict__ out_loss)
{
    const int bid = blockIdx.x;
    const int t = threadIdx.x;

    // ---- shared (compiler sums across paths; each block uses one path) ----
    __shared__ __align__(16) ushort smem[32768];  // expert: A dbuf | B dbuf; reused as Hs[128][136]
    __shared__ int   rid_s[128];
    __shared__ float rgate_s[128];
    __shared__ float b1s[128];
    __shared__ float xs[D_];                      // action
    __shared__ float red[16][A_];                 // action
    __shared__ float ls1[256], ls2[256];          // loss
    __shared__ float mean1, mean2;                // loss

    if (bid == 0) {
        // ================= loss (256-thread version) =================
        float a[4], b[4];
        float pa = 0.f, pb = 0.f;
        #pragma unroll
        for (int j = 0; j < 4; ++j) {
            a[j] = imp[t + 256 * j]; b[j] = loadv[t + 256 * j];
            pa += a[j]; pb += b[j];
        }
        ls1[t] = pa; ls2[t] = pb; __syncthreads();
        for (int s = 128; s > 0; s >>= 1) {
            if (t < s) { ls1[t] += ls1[t + s]; ls2[t] += ls2[t + s]; }
            __syncthreads();
        }
        if (t == 0) { mean1 = ls1[0] / O_; mean2 = ls2[0] / O_; }
        __syncthreads();
        pa = 0.f; pb = 0.f;
        #pragma unroll
        for (int j = 0; j < 4; ++j) {
            float d1 = a[j] - mean1, d2 = b[j] - mean2;
            pa += d1 * d1; pb += d2 * d2;
        }
        ls1[t] = pa; ls2[t] = pb; __syncthreads();
        for (int s = 128; s > 0; s >>= 1) {
            if (t < s) { ls1[t] += ls1[t + s]; ls2[t] += ls2[t + s]; }
            __syncthreads();
        }
        if (t == 0) {
            float var1 = ls1[0] / (O_ - 1), var2 = ls2[0] / (O_ - 1);
            const float eps = 1e-10f;
            out_loss[0] = (var1 / (mean1 * mean1 + eps) + var2 / (mean2 * mean2 + eps)) * LOSS_COEF;
        }
        return;
    }

    if (bid <= 2048) {
        // ================= expert MLP (R1-verified body) =================
        const int id = bid - 1;
        const int ht = id & 15, rt = (id >> 4) & 7, e = id >> 7;
        const int n = cnt[e];
        if (rt * 128 >= n) return;                // uniform early-exit

        const int wv = t >> 6, l = t & 63;
        const int lm = l & 15, q = l >> 4;
        const int wr = wv >> 1, wc = wv & 1;      // 2x2 wave grid

        if (t < 128) {
            int gi = rt * 128 + t;
            rid_s[t]   = (gi < n) ? rows[e * O_ + gi]  : -1;
            rgate_s[t] = (gi < n) ? gatev[e * O_ + gi] : 0.f;
        } else {
            b1s[t - 128] = b1[e * H_ + ht * 128 + (t - 128)];
        }
        __syncthreads();

        // staging: wave-load j covers LDS 16B-slots s=(j*4+wv)*64+l;
        // r = s>>3, cb = l&7; src col-block = cb ^ (r&7).
        const int swe = ((l & 7) ^ (l >> 3)) << 3;
        const ushort* asrc[4];
        const ushort* bsrc[4];
        #pragma unroll
        for (int j = 0; j < 4; ++j) {
            int r = (j * 4 + wv) * 8 + (l >> 3);
            int arow = rid_s[r]; if (arow < 0) arow = 0;
            asrc[j] = obs_bf + (size_t)arow * D_ + swe;
            bsrc[j] = w1T + ((size_t)(e * H_ + ht * 128 + r)) * D_ + swe;
        }

        auto stage = [&](int b, int kc) {
            ushort* ab_ = &smem[b * 8192];
            ushort* bb_ = &smem[16384 + b * 8192];
            const int ko = kc * 64;
            #pragma unroll
            for (int j = 0; j < 4; ++j) {
                gld_lds16(asrc[j] + ko, ab_ + (j * 4 + wv) * 512);
                gld_lds16(bsrc[j] + ko, bb_ + (j * 4 + wv) * 512);
            }
        };

        floatx4 acc[4][4] = {};
        int buf = 0;
        stage(0, 0);
        __syncthreads();

        for (int kc = 0; kc < 16; ++kc) {
            if (kc < 15) stage(buf ^ 1, kc + 1);
            const ushort* ab = &smem[buf * 8192];
            const ushort* bb = &smem[16384 + buf * 8192];
            #pragma unroll
            for (int ks = 0; ks < 2; ++ks) {
                const int co = ((ks * 4 + q) ^ (lm & 7)) << 3;
                fragb a[4];
                #pragma unroll
                for (int i = 0; i < 4; ++i)
                    a[i] = *(const fragb*)(ab + (wr * 64 + i * 16 + lm) * 64 + co);
                #pragma unroll
                for (int nt = 0; nt < 4; ++nt) {
                    fragb b = *(const fragb*)(bb + (wc * 64 + nt * 16 + lm) * 64 + co);
                    #pragma unroll
                    for (int i = 0; i < 4; ++i)
                        acc[i][nt] = __builtin_amdgcn_mfma_f32_16x16x32_bf16(a[i], b, acc[i][nt], 0, 0, 0);
                }
            }
            __syncthreads();
            buf ^= 1;
        }

        // epilogue 1: relu(acc+b1)*gate -> Hs[128][136] bf16
        ushort* Hs = smem;
        #pragma unroll
        for (int i = 0; i < 4; ++i) {
            #pragma unroll
            for (int nt = 0; nt < 4; ++nt) {
                const int col = wc * 64 + nt * 16 + lm;
                const float bb = b1s[col];
                #pragma unroll
                for (int r = 0; r < 4; ++r) {
                    const int row = wr * 64 + i * 16 + q * 4 + r;
                    float h = acc[i][nt][r] + bb;
                    h = h > 0.f ? h : 0.f;
                    Hs[row * 136 + col] = f2bf(h * rgate_s[row]);
                }
            }
        }
        __syncthreads();

        // layer 2: 128x64 y-tile; wave rows wr*64 x a-cols wc*32; K=128
        floatx4 acc2[4][2] = {};
        #pragma unroll
        for (int ks = 0; ks < 4; ++ks) {
            fragb a[4];
            #pragma unroll
            for (int i = 0; i < 4; ++i)
                a[i] = *(const fragb*)(Hs + (wr * 64 + i * 16 + lm) * 136 + ks * 32 + q * 8);
            #pragma unroll
            for (int nt = 0; nt < 2; ++nt) {
                const int acol = wc * 32 + nt * 16 + lm;
                fragb b = *(const fragb*)(w2T + ((size_t)(e * A_ + acol)) * H_ + ht * 128 + ks * 32 + q * 8);
                #pragma unroll
                for (int i = 0; i < 4; ++i)
                    acc2[i][nt] = __builtin_amdgcn_mfma_f32_16x16x32_bf16(a[i], b, acc2[i][nt], 0, 0, 0);
            }
        }

        // epilogue 2: scatter-add into y
        #pragma unroll
        for (int i = 0; i < 4; ++i) {
            #pragma unroll
            for (int r = 0; r < 4; ++r) {
                const int row = wr * 64 + i * 16 + q * 4 + r;
                const int orow = rid_s[row];
                if (orow >= 0) {
                    #pragma unroll
                    for (int nt = 0; nt < 2; ++nt)
                        atomicAdd(&y[(size_t)orow * A_ + wc * 32 + nt * 16 + lm], acc2[i][nt][r]);
                }
            }
        }
        return;
    }

    // ================= action head =================
    {
        const int o = bid - 2049;

        const float4* xrow = (const float4*)(obs + (size_t)o * D_);
        for (int i = t; i < D_ / 4; i += 256) ((float4*)xs)[i] = xrow[i];
        __syncthreads();

        const int a4 = t & 15, dg = t >> 4;
        const float* lw = last_w + (size_t)o * (D_ * A_);
        float acc0 = 0.f, acc1 = 0.f, acc2 = 0.f, acc3 = 0.f;
        #pragma unroll 8
        for (int i = 0; i < D_ / 16; ++i) {
            int d = dg + (i << 4);
            float4 w = *(const float4*)(lw + (size_t)d * A_ + a4 * 4);  // coalesced
            float x = xs[d];
            acc0 += x * w.x; acc1 += x * w.y; acc2 += x * w.z; acc3 += x * w.w;
        }
        *(float4*)&red[dg][a4 * 4] = make_float4(acc0, acc1, acc2, acc3);
        __syncthreads();

        if (t < A_) {   // one wave does the softmax
            float mu = last_b[(size_t)o * A_ + t];
            #pragma unroll
            for (int g = 0; g < 16; ++g) mu += red[g][t];
            float mx = mu;
            #pragma unroll
            for (int off = 32; off > 0; off >>= 1) mx = fmaxf(mx, __shfl_xor(mx, off, 64));
            float ex = expf(mu - mx);
            if (ex < FLT_MIN_NORMAL) ex = 0.f;            // software FTZ
            float s = ex;
            #pragma unroll
            for (int off = 32; off > 0; off >>= 1) s += __shfl_xor(s, off, 64);
            float p = ex / s;
            if (p < FLT_MIN_NORMAL) p = 0.f;              // software FTZ
            probs[(size_t)o * A_ + t] = p;
            float z = (p == 0.f) ? 1e-8f : 0.f;
            logprobs[(size_t)o * A_ + t] = logf(p + z);
        }
    }
}

// ---------------------------------------------------------------------------
extern "C" void kernel_launch(void* const* d_in, const int* in_sizes, int n_in,
                              void* d_out, int out_size, void* d_ws, size_t ws_size,
                              hipStream_t stream)
{
    const float* obs    = (const float*)d_in[0];
    const float* w_gate = (const float*)d_in[1];
    const float* w1     = (const float*)d_in[2];
    const float* b1     = (const float*)d_in[3];
    const float* w2     = (const float*)d_in[4];
    const float* b2     = (const float*)d_in[5];
    const float* last_w = (const float*)d_in[6];
    const float* last_b = (const float*)d_in[7];

    float* out   = (float*)d_out;
    float* probs = out;                 // [O,A]
    float* logp  = out + O_ * A_;       // [O,A]
    float* yout  = out + 2 * O_ * A_;   // [O,A]
    float* loss  = out + 3 * O_ * A_;   // [1]

    char* ws = (char*)d_ws;
    float*  imp       = (float*)(ws + (32 << 10));          // 4 KB
    float*  loadv     = (float*)(ws + (36 << 10));          // 4 KB
    int*    cnt       = (int*)(ws + (40 << 10));            // 64 B
    int*    rows      = (int*)(ws + (41 << 10));            // 64 KB
    float*  gatev     = (float*)(ws + (105 << 10));         // 64 KB
    ushort* obs_bf    = (ushort*)(ws + (256 << 10));        // 2 MB
    ushort* w1T       = (ushort*)(ws + (256 << 10) + (2 << 20));   // 64 MB
    ushort* w2T       = (ushort*)(ws + (256 << 10) + (66 << 20));  // 4 MB

    // K1: zero_cnt + transpose w1 + transpose w2
    hipLaunchKernelGGL(prep_kernel, dim3(1 + 8192 + 512), dim3(256), 0, stream,
                       w1, w2, w1T, w2T, cnt);
    // K2: gating + build_dispatch + y_init + cvt_obs
    hipLaunchKernelGGL(gating_kernel, dim3(O_), dim3(256), 0, stream,
                       obs, w_gate, b2, cnt, rows, gatev, imp, loadv, obs_bf, yout);
    // K3: loss + expert MLP + action head
    hipLaunchKernelGGL(mega_kernel, dim3(1 + 2048 + 1024), dim3(256), 0, stream,
                       obs_bf, w1T, b1, w2T, cnt, rows, gatev, yout,
                       obs, last_w, last_b, probs, logp, imp, loadv, loss);
}

// Round 3
// 553.122 us; speedup vs baseline: 1.2479x; 1.0301x over previous
//
#include <hip/hip_runtime.h>
#include <hip/hip_bf16.h>
#include <math.h>

#define O_ 1024
#define D_ 1024
#define E_ 16
#define K_ 4
#define H_ 2048
#define A_ 64
#define LOSS_COEF 0.01f

// np reference runs FTZ/DAZ (its min logprob is log(FLT_MIN)); gfx950 keeps
// IEEE denormals. Software-flush at the two decision points. (R1-verified.)
#define FLT_MIN_NORMAL 1.17549435e-38f

using floatx4 = __attribute__((ext_vector_type(4))) float;
using fragb   = __attribute__((ext_vector_type(8))) short;   // 8 bf16 in 4 VGPRs

static __device__ __forceinline__ ushort f2bf(float f) {
    // round-to-nearest-even fp32 -> bf16
    unsigned u = __builtin_bit_cast(unsigned, f);
    u += 0x7fffu + ((u >> 16) & 1u);
    return (ushort)(u >> 16);
}

// async global->LDS, 16B per lane; LDS dest = wave-uniform base + lane*16,
// global src is per-lane (so gathers + pre-swizzled sources are fine).
static __device__ __forceinline__ void gld_lds16(const void* g, void* l) {
    __builtin_amdgcn_global_load_lds(
        (const __attribute__((address_space(1))) void*)g,
        (__attribute__((address_space(3))) void*)l, 16, 0, 0);
}

// ---------------------------------------------------------------------------
// K1 "front": blocks 0..1023 = gating (+dispatch scatter, y_init, cvt_obs);
// blocks 1024..9215 = w1 transpose; 9216..9727 = w2 transpose.
// LDS is a 9.3 KB union -> high occupancy for both paths.
// cnt[] is zeroed by hipMemsetAsync before this kernel.
// ---------------------------------------------------------------------------
__global__ __launch_bounds__(256) void front_kernel(
    const float* __restrict__ obs, const float* __restrict__ w_gate,
    const float* __restrict__ b2,
    const float* __restrict__ w1, const float* __restrict__ w2,
    int* __restrict__ cnt, int* __restrict__ rows, float* __restrict__ gatev,
    float* __restrict__ imp, float* __restrict__ loadv,
    ushort* __restrict__ obs_bf, float* __restrict__ yout,
    ushort* __restrict__ w1T, ushort* __restrict__ w2T)
{
    const int bid = blockIdx.x;
    const int t = threadIdx.x;
    __shared__ __align__(16) char sh[9344];       // union: gating 9312B | transpose tile 9216B

    if (bid < 1024) {
        // ================= gating =================
        const int o = bid;
        float* xs            = (float*)sh;                 // [1024]
        float (*part)[20]    = (float(*)[20])(sh + 4096);  // [64][20]
        float* logits        = (float*)(sh + 9216);        // [16]
        int*   sidx          = (int*)(sh + 9280);          // [4]
        float* sgate         = (float*)(sh + 9296);        // [4]

        const float4* xrow = (const float4*)(obs + (size_t)o * D_);
        for (int i = t; i < D_ / 4; i += 256) ((float4*)xs)[i] = xrow[i];
        __syncthreads();

        const int dg = t >> 2, e4 = t & 3;
        const float4* wg = (const float4*)(w_gate + (size_t)o * (D_ * E_));
        float4 acc = make_float4(0.f, 0.f, 0.f, 0.f);
        #pragma unroll 4
        for (int i = 0; i < 16; ++i) {
            int d = dg + (i << 6);
            float4 w = wg[d * 4 + e4];     // f4 idx = t + 256*i : coalesced 16B/lane
            float x = xs[d];
            acc.x += x * w.x; acc.y += x * w.y; acc.z += x * w.z; acc.w += x * w.w;
        }
        *(float4*)&part[dg][e4 * 4] = acc;
        __syncthreads();
        if (t < E_) {
            float s = 0.f;
            for (int g = 0; g < 64; ++g) s += part[g][t];
            logits[t] = s;
        }
        __syncthreads();
        if (t == 0) {
            float lv[E_];
            #pragma unroll
            for (int i = 0; i < E_; ++i) lv[i] = logits[i];
            int idx[K_]; float val[K_];
            bool used[E_] = {};
            for (int k = 0; k < K_; ++k) {            // desc, ties -> lower idx
                int bi = 0; float bv = -INFINITY;
                for (int i = 0; i < E_; ++i)
                    if (!used[i] && lv[i] > bv) { bv = lv[i]; bi = i; }
                used[bi] = true; idx[k] = bi; val[k] = bv;
            }
            float m = val[0];
            float ex[K_]; float s = 0.f;
            for (int k = 0; k < K_; ++k) { ex[k] = expf(val[k] - m); s += ex[k]; }
            float inv = 1.f / s;
            float sumg = 0.f; int ld = 0;
            for (int k = 0; k < K_; ++k) {
                float g = ex[k] * inv;
                sidx[k] = idx[k]; sgate[k] = g;
                int pos = atomicAdd(&cnt[idx[k]], 1);
                rows[idx[k] * O_ + pos]  = o;
                gatev[idx[k] * O_ + pos] = g;
                sumg += g;
                if (g > 0.f) ld++;
            }
            imp[o] = sumg;
            loadv[o] = (float)ld;
        }

        // fused cvt_obs: xs -> bf16 row (overlaps thread-0 top-k)
        {
            float4 v = ((const float4*)xs)[t];        // 256 f4 = 1024 floats
            ushort4 u;
            u.x = f2bf(v.x); u.y = f2bf(v.y); u.z = f2bf(v.z); u.w = f2bf(v.w);
            ((ushort4*)(obs_bf + (size_t)o * D_))[t] = u;
        }
        __syncthreads();

        // fused y_init: y[o,a] = sum_k gate_k * b2[e_k,a]
        if (t < A_) {
            float accy = 0.f;
            #pragma unroll
            for (int k = 0; k < K_; ++k)
                accy += sgate[k] * b2[sidx[k] * A_ + t];
            yout[(size_t)o * A_ + t] = accy;
        }
        return;
    }

    // ================= transpose: src[E][R][C] f32 -> dst[E][C][R] bf16 ====
    {
        int id = bid - 1024;
        const float* src; ushort* dst; int R, C, c0, r0, e;
        if (id < 8192) {                      // w1: R=D, C=H
            c0 = (id & 31) * 64; r0 = ((id >> 5) & 15) * 64; e = id >> 9;
            src = w1; dst = w1T; R = D_; C = H_;
        } else {                              // w2: R=H, C=A (one c-tile)
            id -= 8192;
            c0 = 0; r0 = (id & 31) * 64; e = id >> 5;
            src = w2; dst = w2T; R = H_; C = A_;
        }

        ushort (*tile)[72] = (ushort(*)[72])sh;   // [64][72], +8 pad
        const float* s = src + (size_t)e * R * C;
        const int rr = t >> 4, cq = t & 15;
        #pragma unroll
        for (int i = 0; i < 4; ++i) {
            int r = rr + i * 16;
            float4 v = *(const float4*)(s + (size_t)(r0 + r) * C + c0 + cq * 4);
            ushort4 u;
            u.x = f2bf(v.x); u.y = f2bf(v.y); u.z = f2bf(v.z); u.w = f2bf(v.w);
            *(ushort4*)&tile[r][cq * 4] = u;
        }
        __syncthreads();
        ushort* dbase = dst + (size_t)e * R * C;
        const int cc = t >> 4, rq = t & 15;
        #pragma unroll
        for (int i = 0; i < 4; ++i) {
            int c = cc + i * 16;
            ushort4 u;
            u.x = tile[rq * 4 + 0][c];
            u.y = tile[rq * 4 + 1][c];
            u.z = tile[rq * 4 + 2][c];
            u.w = tile[rq * 4 + 3][c];
            *(ushort4*)(dbase + (size_t)(c0 + c) * R + r0 + rq * 4) = u;
        }
    }
}

// ---------------------------------------------------------------------------
// K2 "mega": block 0 = loss; blocks 1..2048 = expert MLP; 2049..3072 = action.
// LDS diet vs R2: expert is SINGLE-buffered (stage -> barrier -> compute ->
// barrier; the m99/m100 result says dbuf buys nothing once >=3 blocks/CU of
// TLP exist), and action/loss scratch overlays smem. Total 36.4 KB -> 4
// blocks/CU (launch_bounds(256,4)) so the action head's streaming regains
// occupancy. Expert ids are XCD-paired: all rt of one (e,ht) share bid%8 ->
// same-XCD L2 reuse of the 256 KB w1T panel (T1).
// Expert compute/swizzle index math byte-identical to the R1-verified kernel.
// ---------------------------------------------------------------------------
__global__ __launch_bounds__(256, 4) void mega_kernel(
    const ushort* __restrict__ obs_bf, const ushort* __restrict__ w1T,
    const float* __restrict__ b1, const ushort* __restrict__ w2T,
    const int* __restrict__ cnt, const int* __restrict__ rows,
    const float* __restrict__ gatev, float* __restrict__ y,
    const float* __restrict__ obs, const float* __restrict__ last_w,
    const float* __restrict__ last_b,
    float* __restrict__ probs, float* __restrict__ logprobs,
    const float* __restrict__ imp, const float* __restrict__ loadv,
    float* __restrict__ out_loss)
{
    const int bid = blockIdx.x;
    const int t = threadIdx.x;

    // 34816 B: expert A-buf[0..8192) | B-buf[8192..16384) ushorts; reused as
    // Hs[128][136]. Action overlays xs(4KB)+red(4KB); loss overlays ls1/ls2.
    __shared__ __align__(16) ushort smem[17408];
    __shared__ int   rid_s[128];
    __shared__ float rgate_s[128];
    __shared__ float b1s[128];
    __shared__ float mean1, mean2;

    if (bid == 0) {
        // ================= loss =================
        float* ls1 = (float*)smem;            // [256]
        float* ls2 = ls1 + 256;               // [256]
        float a[4], b[4];
        float pa = 0.f, pb = 0.f;
        #pragma unroll
        for (int j = 0; j < 4; ++j) {
            a[j] = imp[t + 256 * j]; b[j] = loadv[t + 256 * j];
            pa += a[j]; pb += b[j];
        }
        ls1[t] = pa; ls2[t] = pb; __syncthreads();
        for (int s = 128; s > 0; s >>= 1) {
            if (t < s) { ls1[t] += ls1[t + s]; ls2[t] += ls2[t + s]; }
            __syncthreads();
        }
        if (t == 0) { mean1 = ls1[0] / O_; mean2 = ls2[0] / O_; }
        __syncthreads();
        pa = 0.f; pb = 0.f;
        #pragma unroll
        for (int j = 0; j < 4; ++j) {
            float d1 = a[j] - mean1, d2 = b[j] - mean2;
            pa += d1 * d1; pb += d2 * d2;
        }
        ls1[t] = pa; ls2[t] = pb; __syncthreads();
        for (int s = 128; s > 0; s >>= 1) {
            if (t < s) { ls1[t] += ls1[t + s]; ls2[t] += ls2[t + s]; }
            __syncthreads();
        }
        if (t == 0) {
            float var1 = ls1[0] / (O_ - 1), var2 = ls2[0] / (O_ - 1);
            const float eps = 1e-10f;
            out_loss[0] = (var1 / (mean1 * mean1 + eps) + var2 / (mean2 * mean2 + eps)) * LOSS_COEF;
        }
        return;
    }

    if (bid <= 2048) {
        // ================= expert MLP =================
        // XCD-paired id decode: flat = (p&7) + 8*(r + 8*(p>>3)); p=(e,ht).
        const int id  = bid - 1;
        const int xcd = id & 7;
        const int r8  = (id >> 3) & 7;
        const int phi = id >> 6;
        const int p   = (phi << 3) | xcd;
        const int e   = p >> 4, ht = p & 15, rt = r8;
        const int n = cnt[e];
        if (rt * 128 >= n) return;                // uniform early-exit

        const int wv = t >> 6, l = t & 63;
        const int lm = l & 15, q = l >> 4;
        const int wr = wv >> 1, wc = wv & 1;      // 2x2 wave grid

        if (t < 128) {
            int gi = rt * 128 + t;
            rid_s[t]   = (gi < n) ? rows[e * O_ + gi]  : -1;
            rgate_s[t] = (gi < n) ? gatev[e * O_ + gi] : 0.f;
        } else {
            b1s[t - 128] = b1[e * H_ + ht * 128 + (t - 128)];
        }
        __syncthreads();

        // staging: wave-load j covers LDS 16B-slots s=(j*4+wv)*64+l;
        // r = s>>3, cb = l&7; src col-block = cb ^ (r&7).  (R1-verified)
        const int swe = ((l & 7) ^ (l >> 3)) << 3;
        const ushort* asrc[4];
        const ushort* bsrc[4];
        #pragma unroll
        for (int j = 0; j < 4; ++j) {
            int r = (j * 4 + wv) * 8 + (l >> 3);
            int arow = rid_s[r]; if (arow < 0) arow = 0;
            asrc[j] = obs_bf + (size_t)arow * D_ + swe;
            bsrc[j] = w1T + ((size_t)(e * H_ + ht * 128 + r)) * D_ + swe;
        }

        auto stage = [&](int kc) {
            ushort* ab_ = &smem[0];
            ushort* bb_ = &smem[8192];
            const int ko = kc * 64;
            #pragma unroll
            for (int j = 0; j < 4; ++j) {
                gld_lds16(asrc[j] + ko, ab_ + (j * 4 + wv) * 512);
                gld_lds16(bsrc[j] + ko, bb_ + (j * 4 + wv) * 512);
            }
        };

        // single-buffered K loop (TLP from 4 blocks/CU hides staging latency)
        floatx4 acc[4][4] = {};
        const ushort* ab = &smem[0];
        const ushort* bb = &smem[8192];
        for (int kc = 0; kc < 16; ++kc) {
            stage(kc);
            __syncthreads();                  // drains vmcnt -> chunk visible
            #pragma unroll
            for (int ks = 0; ks < 2; ++ks) {
                const int co = ((ks * 4 + q) ^ (lm & 7)) << 3;
                fragb a[4];
                #pragma unroll
                for (int i = 0; i < 4; ++i)
                    a[i] = *(const fragb*)(ab + (wr * 64 + i * 16 + lm) * 64 + co);
                #pragma unroll
                for (int nt = 0; nt < 4; ++nt) {
                    fragb b = *(const fragb*)(bb + (wc * 64 + nt * 16 + lm) * 64 + co);
                    #pragma unroll
                    for (int i = 0; i < 4; ++i)
                        acc[i][nt] = __builtin_amdgcn_mfma_f32_16x16x32_bf16(a[i], b, acc[i][nt], 0, 0, 0);
                }
            }
            __syncthreads();                  // all reads done before next stage
        }

        // epilogue 1: relu(acc+b1)*gate -> Hs[128][136] bf16
        ushort* Hs = smem;
        #pragma unroll
        for (int i = 0; i < 4; ++i) {
            #pragma unroll
            for (int nt = 0; nt < 4; ++nt) {
                const int col = wc * 64 + nt * 16 + lm;
                const float bb2 = b1s[col];
                #pragma unroll
                for (int r = 0; r < 4; ++r) {
                    const int row = wr * 64 + i * 16 + q * 4 + r;
                    float h = acc[i][nt][r] + bb2;
                    h = h > 0.f ? h : 0.f;
                    Hs[row * 136 + col] = f2bf(h * rgate_s[row]);
                }
            }
        }
        __syncthreads();

        // layer 2: 128x64 y-tile; wave rows wr*64 x a-cols wc*32; K=128
        floatx4 acc2[4][2] = {};
        #pragma unroll
        for (int ks = 0; ks < 4; ++ks) {
            fragb a[4];
            #pragma unroll
            for (int i = 0; i < 4; ++i)
                a[i] = *(const fragb*)(Hs + (wr * 64 + i * 16 + lm) * 136 + ks * 32 + q * 8);
            #pragma unroll
            for (int nt = 0; nt < 2; ++nt) {
                const int acol = wc * 32 + nt * 16 + lm;
                fragb b = *(const fragb*)(w2T + ((size_t)(e * A_ + acol)) * H_ + ht * 128 + ks * 32 + q * 8);
                #pragma unroll
                for (int i = 0; i < 4; ++i)
                    acc2[i][nt] = __builtin_amdgcn_mfma_f32_16x16x32_bf16(a[i], b, acc2[i][nt], 0, 0, 0);
            }
        }

        // epilogue 2: scatter-add into y
        #pragma unroll
        for (int i = 0; i < 4; ++i) {
            #pragma unroll
            for (int r = 0; r < 4; ++r) {
                const int row = wr * 64 + i * 16 + q * 4 + r;
                const int orow = rid_s[row];
                if (orow >= 0) {
                    #pragma unroll
                    for (int nt = 0; nt < 2; ++nt)
                        atomicAdd(&y[(size_t)orow * A_ + wc * 32 + nt * 16 + lm], acc2[i][nt][r]);
                }
            }
        }
        return;
    }

    // ================= action head =================
    {
        const int o = bid - 2049;
        float* xs = (float*)smem;                     // [1024]
        float (*red)[A_] = (float(*)[A_])(smem + 2048);   // [16][64] @ +4KB

        const float4* xrow = (const float4*)(obs + (size_t)o * D_);
        for (int i = t; i < D_ / 4; i += 256) ((float4*)xs)[i] = xrow[i];
        __syncthreads();

        const int a4 = t & 15, dg = t >> 4;
        const float* lw = last_w + (size_t)o * (D_ * A_);
        float acc0 = 0.f, acc1 = 0.f, acc2 = 0.f, acc3 = 0.f;
        #pragma unroll 8
        for (int i = 0; i < D_ / 16; ++i) {
            int d = dg + (i << 4);
            float4 w = *(const float4*)(lw + (size_t)d * A_ + a4 * 4);  // coalesced
            float x = xs[d];
            acc0 += x * w.x; acc1 += x * w.y; acc2 += x * w.z; acc3 += x * w.w;
        }
        *(float4*)&red[dg][a4 * 4] = make_float4(acc0, acc1, acc2, acc3);
        __syncthreads();

        if (t < A_) {   // one wave does the softmax
            float mu = last_b[(size_t)o * A_ + t];
            #pragma unroll
            for (int g = 0; g < 16; ++g) mu += red[g][t];
            float mx = mu;
            #pragma unroll
            for (int off = 32; off > 0; off >>= 1) mx = fmaxf(mx, __shfl_xor(mx, off, 64));
            float ex = expf(mu - mx);
            if (ex < FLT_MIN_NORMAL) ex = 0.f;            // software FTZ
            float s = ex;
            #pragma unroll
            for (int off = 32; off > 0; off >>= 1) s += __shfl_xor(s, off, 64);
            float p = ex / s;
            if (p < FLT_MIN_NORMAL) p = 0.f;              // software FTZ
            probs[(size_t)o * A_ + t] = p;
            float z = (p == 0.f) ? 1e-8f : 0.f;
            logprobs[(size_t)o * A_ + t] = logf(p + z);
        }
    }
}

// ---------------------------------------------------------------------------
extern "C" void kernel_launch(void* const* d_in, const int* in_sizes, int n_in,
                              void* d_out, int out_size, void* d_ws, size_t ws_size,
                              hipStream_t stream)
{
    const float* obs    = (const float*)d_in[0];
    const float* w_gate = (const float*)d_in[1];
    const float* w1     = (const float*)d_in[2];
    const float* b1     = (const float*)d_in[3];
    const float* w2     = (const float*)d_in[4];
    const float* b2     = (const float*)d_in[5];
    const float* last_w = (const float*)d_in[6];
    const float* last_b = (const float*)d_in[7];

    float* out   = (float*)d_out;
    float* probs = out;                 // [O,A]
    float* logp  = out + O_ * A_;       // [O,A]
    float* yout  = out + 2 * O_ * A_;   // [O,A]
    float* loss  = out + 3 * O_ * A_;   // [1]

    char* ws = (char*)d_ws;
    float*  imp       = (float*)(ws + (32 << 10));          // 4 KB
    float*  loadv     = (float*)(ws + (36 << 10));          // 4 KB
    int*    cnt       = (int*)(ws + (40 << 10));            // 64 B
    int*    rows      = (int*)(ws + (41 << 10));            // 64 KB
    float*  gatev     = (float*)(ws + (105 << 10));         // 64 KB
    ushort* obs_bf    = (ushort*)(ws + (256 << 10));        // 2 MB
    ushort* w1T       = (ushort*)(ws + (256 << 10) + (2 << 20));   // 64 MB
    ushort* w2T       = (ushort*)(ws + (256 << 10) + (66 << 20));  // 4 MB

    hipMemsetAsync(cnt, 0, E_ * sizeof(int), stream);       // capture-safe

    // K1: gating(+dispatch+y_init+cvt_obs) + transpose w1 + transpose w2
    hipLaunchKernelGGL(front_kernel, dim3(1024 + 8192 + 512), dim3(256), 0, stream,
                       obs, w_gate, b2, w1, w2,
                       cnt, rows, gatev, imp, loadv, obs_bf, yout, w1T, w2T);
    // K2: loss + expert MLP + action head
    hipLaunchKernelGGL(mega_kernel, dim3(1 + 2048 + 1024), dim3(256), 0, stream,
                       obs_bf, w1T, b1, w2T, cnt, rows, gatev, yout,
                       obs, last_w, last_b, probs, logp, imp, loadv, loss);
}